// Round 1
// baseline (25.329 us; speedup 1.0000x reference)
//
#include <hip/hip_runtime.h>

// Entropic water-filling:
//   w_i = min(c, exp(x_i - nu)),  nu s.t. sum_i w_i = 1,  c = 0.02, N = 512.
// Substitute u = exp(-nu), e_i = exp(x_i):  w_i = min(c, e_i * u).
// Active-set fixed point (monotone, converges in <= |active|+1 iterations):
//   u_0 = 1/S,  A_t = { e_i >= c/u_t },  u_{t+1} = (1 - c|A_t|) / (S - sum_{A_t} e_i).
// One wave (64 lanes) per row, 8 elements per lane; butterfly shuffle reductions.

#define N_ASSETS 512
#define C_CAP 0.02f
#define ROWS_PER_BLOCK 4   // 256 threads = 4 waves, one row per wave

__global__ __launch_bounds__(256, 4) void waterfill_kernel(
    const float* __restrict__ x, float* __restrict__ out, int n_rows) {
  const int wave = threadIdx.x >> 6;
  const int lane = threadIdx.x & 63;
  const int row = blockIdx.x * ROWS_PER_BLOCK + wave;
  if (row >= n_rows) return;

  const float* xr = x + (size_t)row * N_ASSETS;
  float* wr = out + (size_t)row * N_ASSETS;

  // Coalesced: lane i reads float4 at 16B*i and at 1024B + 16B*i.
  float4 a = reinterpret_cast<const float4*>(xr)[lane];
  float4 b = reinterpret_cast<const float4*>(xr)[lane + 64];

  float e[8];
  e[0] = __expf(a.x); e[1] = __expf(a.y); e[2] = __expf(a.z); e[3] = __expf(a.w);
  e[4] = __expf(b.x); e[5] = __expf(b.y); e[6] = __expf(b.z); e[7] = __expf(b.w);

  // S = sum of all e_i in the row (pairwise local, butterfly across wave).
  float S = ((e[0] + e[1]) + (e[2] + e[3])) + ((e[4] + e[5]) + (e[6] + e[7]));
#pragma unroll
  for (int m = 1; m < 64; m <<= 1) S += __shfl_xor(S, m, 64);

  float u = 1.0f / S;  // exact solution if nothing is capped
  int kprev = -1;
  for (int it = 0; it < 50; ++it) {
    const float th = C_CAP / u;  // e_i >= th  <=>  e_i * u >= c
    float s_act = 0.0f, cnt = 0.0f;
#pragma unroll
    for (int j = 0; j < 8; ++j) {
      const bool act = e[j] >= th;
      s_act += act ? e[j] : 0.0f;
      cnt += act ? 1.0f : 0.0f;
    }
#pragma unroll
    for (int m = 1; m < 64; m <<= 1) {
      s_act += __shfl_xor(s_act, m, 64);
      cnt += __shfl_xor(cnt, m, 64);
    }
    // Butterfly gives bit-identical values on all lanes -> uniform branch.
    const int k = (int)cnt;
    const float r = fmaxf(1.0f - C_CAP * cnt, 1e-12f);   // residual mass
    const float Sin = fmaxf(S - s_act, 1e-30f);          // sum over inactive
    u = r / Sin;  // exact u for this active set
    if (k == kprev) break;  // set unchanged -> fixed point (u just recomputed identically)
    kprev = k;
  }

  float4 oa, ob;
  oa.x = fminf(C_CAP, e[0] * u);
  oa.y = fminf(C_CAP, e[1] * u);
  oa.z = fminf(C_CAP, e[2] * u);
  oa.w = fminf(C_CAP, e[3] * u);
  ob.x = fminf(C_CAP, e[4] * u);
  ob.y = fminf(C_CAP, e[5] * u);
  ob.z = fminf(C_CAP, e[6] * u);
  ob.w = fminf(C_CAP, e[7] * u);
  reinterpret_cast<float4*>(wr)[lane] = oa;
  reinterpret_cast<float4*>(wr)[lane + 64] = ob;
}

extern "C" void kernel_launch(void* const* d_in, const int* in_sizes, int n_in,
                              void* d_out, int out_size, void* d_ws, size_t ws_size,
                              hipStream_t stream) {
  const float* x = (const float*)d_in[0];
  float* out = (float*)d_out;
  const int n_rows = in_sizes[0] / N_ASSETS;
  const int grid = (n_rows + ROWS_PER_BLOCK - 1) / ROWS_PER_BLOCK;
  waterfill_kernel<<<grid, 256, 0, stream>>>(x, out, n_rows);
}